// Round 10
// baseline (389.630 us; speedup 1.0000x reference)
//
#include <hip/hip_runtime.h>
#include <hip/hip_bf16.h>

#define N_NODES 50000
#define DIM 128
#define E_EDGES 800000
#define L_LAYERS 3
#define MTILES 3125       // 50000/16 exactly
#define NBUCK 98          // ceil(50000/512)
#define BCAP 9216         // bucket capacity: mean 8192 + 11 sigma
#define BSHIFT 9          // 512 nodes per bucket

typedef __attribute__((ext_vector_type(8))) short short8;
typedef __attribute__((ext_vector_type(4))) float f32x4;
typedef __attribute__((ext_vector_type(2))) _Float16 f16x2;
typedef __attribute__((ext_vector_type(4))) _Float16 f16x4;
typedef __attribute__((ext_vector_type(8))) _Float16 f16x8;

// ---- x fp32 -> fp16 ----
__global__ __launch_bounds__(256) void cvt16_kernel(const float4* __restrict__ in,
                                                    f16x4* __restrict__ out) {
    int i = blockIdx.x * 256 + threadIdx.x;
    float4 v = in[i];
    f16x4 o;
    o[0] = (_Float16)v.x; o[1] = (_Float16)v.y;
    o[2] = (_Float16)v.z; o[3] = (_Float16)v.w;
    out[i] = o;
}

// ---- W1,W2 [L][K][Nn] fp32 -> fragment-contiguous fp16 ----
__global__ __launch_bounds__(256) void trans_f16_kernel(
        const float* __restrict__ w1, const float* __restrict__ w2,
        _Float16* __restrict__ f1, _Float16* __restrict__ f2) {
    int idx = blockIdx.x * 256 + threadIdx.x;
    const int per = DIM * 2 * DIM;             // 32768
    const int tot = L_LAYERS * per;
    const float* w;
    _Float16* f;
    int K, Nn, id;
    if (idx < tot) { w = w1; f = f1; K = DIM; Nn = 2 * DIM; id = idx; }
    else           { w = w2; f = f2; K = 2 * DIM; Nn = DIM; id = idx - tot; }
    int l = id / per;
    int r = id - l * per;
    int k = r / Nn;
    int n = r - k * Nn;
    int KS = K >> 5;
    int off = ((((n >> 4) * KS + (k >> 5)) * 4 + ((k >> 3) & 3)) * 16 + (n & 15)) * 8 + (k & 7);
    f[(size_t)l * per + off] = (_Float16)w[id];
}

// ---- fold bias+BN into per-channel scale/shift ----
__global__ __launch_bounds__(256) void prep_params_kernel(
        const float* __restrict__ b1, const float* __restrict__ g1,
        const float* __restrict__ be1, const float* __restrict__ m1,
        const float* __restrict__ v1, const float* __restrict__ b2,
        const float* __restrict__ go, const float* __restrict__ bo,
        const float* __restrict__ mo, const float* __restrict__ vo,
        float* __restrict__ scale1, float* __restrict__ shift1,
        float* __restrict__ scale2, float* __restrict__ shift2) {
    int idx = blockIdx.x * 256 + threadIdx.x;
    if (idx < L_LAYERS * 256) {
        float s = g1[idx] * rsqrtf(v1[idx] + 1e-5f);
        scale1[idx] = s;
        shift1[idx] = (b1[idx] - m1[idx]) * s + be1[idx];
    }
    int idx2 = idx - L_LAYERS * 256;
    if (idx2 >= 0 && idx2 < L_LAYERS * 128) {
        int l = idx2 >> 7;
        if (l < L_LAYERS - 1) {
            float s = go[idx2] * rsqrtf(vo[idx2] + 1e-5f);
            scale2[idx2] = s;
            shift2[idx2] = (b2[idx2] - mo[idx2]) * s + bo[idx2];
        } else {
            scale2[idx2] = 1.0f;
            shift2[idx2] = b2[idx2];
        }
    }
}

// ================= binned CSR build =================

__global__ void initcur_kernel(int* __restrict__ gcur) {
    int t = threadIdx.x;
    if (t < NBUCK) gcur[t] = t * BCAP;
}

__global__ __launch_bounds__(256) void bin_kernel(const int* __restrict__ ei,
                                                  int* __restrict__ gcur,
                                                  unsigned int* __restrict__ brec) {
    __shared__ int cnt[NBUCK];
    __shared__ int off[NBUCK];
    __shared__ int gbase[NBUCK];
    __shared__ unsigned int rec[4096];
    const int t = threadIdx.x;
    const int start = blockIdx.x * 4096;
    for (int i = t; i < NBUCK; i += 256) cnt[i] = 0;
    __syncthreads();
    unsigned int myrec[16];
    unsigned int mypos[16];
    int nmine = 0;
    #pragma unroll
    for (int i = 0; i < 16; ++i) {
        int e = start + i * 256 + t;
        if (e < E_EDGES) {
            int src = ei[e];
            int dst = ei[E_EDGES + e];
            int b = dst >> BSHIFT;
            int idx = atomicAdd(&cnt[b], 1);
            myrec[i] = ((unsigned int)(dst & 511) << 16) | (unsigned int)src;
            mypos[i] = ((unsigned int)b << 16) | (unsigned int)idx;
            nmine = i + 1;
        }
    }
    __syncthreads();
    if (t == 0) {
        int s = 0;
        for (int b = 0; b < NBUCK; ++b) { off[b] = s; s += cnt[b]; }
    }
    __syncthreads();
    #pragma unroll
    for (int i = 0; i < 16; ++i) {
        if (i < nmine) {
            int b = mypos[i] >> 16;
            int idx = mypos[i] & 0xFFFF;
            rec[off[b] + idx] = myrec[i];
        }
    }
    __syncthreads();
    if (t < NBUCK && cnt[t] > 0) gbase[t] = atomicAdd(&gcur[t], cnt[t]);
    __syncthreads();
    const int wv = t >> 6, lane = t & 63;
    for (int b = wv; b < NBUCK; b += 4) {
        int c = cnt[b], o = off[b], g = gbase[b];
        for (int j = lane; j < c; j += 64)
            brec[g + j] = rec[o + j];
    }
}

__global__ void bscan_kernel(const int* __restrict__ gcur, int* __restrict__ colbase,
                             int* __restrict__ rowp) {
    if (threadIdx.x == 0) {
        int s = 0;
        for (int b = 0; b < NBUCK; ++b) {
            colbase[b] = s;
            s += gcur[b] - b * BCAP;
        }
        rowp[N_NODES] = E_EDGES;
    }
}

__global__ __launch_bounds__(256) void bsort_kernel(const unsigned int* __restrict__ brec,
                                                    const int* __restrict__ gcur,
                                                    const int* __restrict__ colbase,
                                                    int* __restrict__ rowp,
                                                    unsigned short* __restrict__ col) {
    __shared__ int ncnt[512];
    __shared__ int noff[512];
    __shared__ int wsum[4];
    __shared__ unsigned short srcbuf[BCAP];
    const int b = blockIdx.x;
    const int t = threadIdx.x;
    const int lane = t & 63;
    const int wv = t >> 6;
    const int cnt = gcur[b] - b * BCAP;
    const unsigned int* r = brec + (size_t)b * BCAP;
    for (int i = t; i < 512; i += 256) ncnt[i] = 0;
    __syncthreads();
    for (int j = t; j < cnt; j += 256)
        atomicAdd(&ncnt[r[j] >> 16], 1);
    __syncthreads();
    int a0 = ncnt[2 * t], a1 = ncnt[2 * t + 1];
    int pair = a0 + a1;
    int inc = pair;
    #pragma unroll
    for (int d = 1; d < 64; d <<= 1) {
        int u = __shfl_up(inc, d, 64);
        if (lane >= d) inc += u;
    }
    if (lane == 63) wsum[wv] = inc;
    __syncthreads();
    int wo = 0;
    if (wv > 0) wo = wsum[0];
    if (wv > 1) wo += wsum[1];
    if (wv > 2) wo += wsum[2];
    int excl = wo + inc - pair;
    noff[2 * t] = excl;
    noff[2 * t + 1] = excl + a0;
    __syncthreads();
    const int n0 = b << BSHIFT;
    const int cb = colbase[b];
    for (int i = t; i < 512; i += 256) {
        int node = n0 + i;
        if (node < N_NODES) rowp[node] = cb + noff[i];
    }
    for (int i = t; i < 512; i += 256) ncnt[i] = noff[i];
    __syncthreads();
    for (int j = t; j < cnt; j += 256) {
        unsigned int v = r[j];
        int pos = atomicAdd(&ncnt[v >> 16], 1);
        srcbuf[pos] = (unsigned short)(v & 0xFFFFu);
    }
    __syncthreads();
    unsigned short* cp = col + cb;
    for (int j = t; j < cnt; j += 256) cp[j] = srcbuf[j];
}

// ---- aggregation: z = (1+eps)*h[i] + sum_j h[j]; h fp16, z fp16 A-frag order ----
__global__ __launch_bounds__(256) void aggregate_kernel(
        const unsigned int* __restrict__ h16,
        const int* __restrict__ row, const unsigned short* __restrict__ col,
        const float* __restrict__ epsp,
        unsigned short* __restrict__ zf) {
    int wv = threadIdx.x >> 6;
    int lane = threadIdx.x & 63;
    int node = blockIdx.x * 4 + wv;                  // grid = 12500 exactly
    size_t base = (size_t)node * 64;
    float s = 1.0f + epsp[0];
    f16x2 hv = __builtin_bit_cast(f16x2, h16[base + lane]);
    float ax = s * (float)hv[0], ay = s * (float)hv[1];
    int e = row[node], e1 = row[node + 1];
    for (; e + 8 <= e1; e += 8) {
        int c0 = col[e],     c1 = col[e + 1], c2 = col[e + 2], c3 = col[e + 3];
        int c4 = col[e + 4], c5 = col[e + 5], c6 = col[e + 6], c7 = col[e + 7];
        f16x2 v0 = __builtin_bit_cast(f16x2, h16[(size_t)c0 * 64 + lane]);
        f16x2 v1 = __builtin_bit_cast(f16x2, h16[(size_t)c1 * 64 + lane]);
        f16x2 v2 = __builtin_bit_cast(f16x2, h16[(size_t)c2 * 64 + lane]);
        f16x2 v3 = __builtin_bit_cast(f16x2, h16[(size_t)c3 * 64 + lane]);
        f16x2 v4 = __builtin_bit_cast(f16x2, h16[(size_t)c4 * 64 + lane]);
        f16x2 v5 = __builtin_bit_cast(f16x2, h16[(size_t)c5 * 64 + lane]);
        f16x2 v6 = __builtin_bit_cast(f16x2, h16[(size_t)c6 * 64 + lane]);
        f16x2 v7 = __builtin_bit_cast(f16x2, h16[(size_t)c7 * 64 + lane]);
        ax += (((float)v0[0] + (float)v1[0]) + ((float)v2[0] + (float)v3[0]))
            + (((float)v4[0] + (float)v5[0]) + ((float)v6[0] + (float)v7[0]));
        ay += (((float)v0[1] + (float)v1[1]) + ((float)v2[1] + (float)v3[1]))
            + (((float)v4[1] + (float)v5[1]) + ((float)v6[1] + (float)v7[1]));
    }
    for (; e < e1; ++e) {
        f16x2 v = __builtin_bit_cast(f16x2, h16[(size_t)col[e] * 64 + lane]);
        ax += (float)v[0];
        ay += (float)v[1];
    }
    unsigned short ux = __builtin_bit_cast(unsigned short, (_Float16)ax);
    unsigned short uy = __builtin_bit_cast(unsigned short, (_Float16)ay);
    int mt = node >> 4, r16 = node & 15;
    int ks = lane >> 4, quad = (lane >> 2) & 3, jb = (lane * 2) & 7;
    size_t zo = (((size_t)(mt * 4 + ks)) * 4 + quad) * 128 + r16 * 8 + jb;
    *(ushort2*)(zf + zo) = make_ushort2(ux, uy);
}

// ---- fused MLP, pure fp16 MFMA, 1 wave/block (16 rows), K-chunked LDS ----
__global__ __launch_bounds__(64) void mlp_kernel(
        const _Float16* __restrict__ zf,
        const _Float16* __restrict__ w1f, const _Float16* __restrict__ w2f,
        const float* __restrict__ scale1, const float* __restrict__ shift1,
        const float* __restrict__ scale2, const float* __restrict__ shift2,
        int last,
        unsigned short* __restrict__ h16out, float* __restrict__ lsout) {
    __shared__ _Float16 tbuf[2176];   // 16 planes * 136
    const int lane = threadIdx.x;
    const int quad = lane >> 4;
    const int l16 = lane & 15;
    const int mt = blockIdx.x;
    const int R0 = mt * 16;

    f16x8 ah[4];
    #pragma unroll
    for (int ks = 0; ks < 4; ++ks)
        ah[ks] = *(const f16x8*)(zf + (((size_t)(mt * 4 + ks)) << 9) + lane * 8);

    f32x4 acc2[8] = {};
    #pragma unroll
    for (int c = 0; c < 2; ++c) {
        // phase 1 chunk: hidden cols [128c, 128c+128) -> LDS planes 0..15
        #pragma unroll
        for (int ntl = 0; ntl < 8; ++ntl) {
            int nt = c * 8 + ntl;
            f32x4 acc = {};
            #pragma unroll
            for (int ks = 0; ks < 4; ++ks) {
                f16x8 b = *(const f16x8*)(w1f + (((size_t)(nt * 4 + ks)) << 9) + lane * 8);
                acc = __builtin_amdgcn_mfma_f32_16x16x32_f16(ah[ks], b, acc, 0, 0, 0);
            }
            int cg = nt * 16 + l16;
            float sc = scale1[cg];
            float sh = shift1[cg];
            int plane = (cg >> 3) & 15;
            int basei = plane * 136 + (cg & 7);
            #pragma unroll
            for (int r = 0; r < 4; ++r) {
                float val = fmaxf(acc[r] * sc + sh, 0.0f);
                tbuf[basei + (quad * 4 + r) * 8] = (_Float16)val;
            }
        }
        // phase 2 chunk: k in [128c, 128c+128)
        #pragma unroll
        for (int ks4 = 0; ks4 < 4; ++ks4) {
            int po = (ks4 * 4 + quad) * 136 + l16 * 8;
            f16x8 a2 = *(const f16x8*)&tbuf[po];
            int ksg = c * 4 + ks4;
            #pragma unroll
            for (int nt = 0; nt < 8; ++nt) {
                f16x8 b = *(const f16x8*)(w2f + (((size_t)(nt * 8 + ksg)) << 9) + lane * 8);
                acc2[nt] = __builtin_amdgcn_mfma_f32_16x16x32_f16(a2, b, acc2[nt], 0, 0, 0);
            }
        }
    }

    #pragma unroll
    for (int nt = 0; nt < 8; ++nt) {
        int cg = nt * 16 + l16;
        float sc = scale2[cg];
        float sh = shift2[cg];
        #pragma unroll
        for (int r = 0; r < 4; ++r)
            acc2[nt][r] = acc2[nt][r] * sc + sh;
    }
    if (!last) {
        #pragma unroll
        for (int nt = 0; nt < 8; ++nt) {
            int cg = nt * 16 + l16;
            #pragma unroll
            for (int r = 0; r < 4; ++r) {
                int rg = R0 + quad * 4 + r;
                float val = fmaxf(acc2[nt][r], 0.0f);
                h16out[(size_t)rg * DIM + cg] =
                    __builtin_bit_cast(unsigned short, (_Float16)val);
            }
        }
    } else {
        #pragma unroll
        for (int r = 0; r < 4; ++r) {
            float mx = acc2[0][r];
            #pragma unroll
            for (int nt = 1; nt < 8; ++nt) mx = fmaxf(mx, acc2[nt][r]);
            #pragma unroll
            for (int off = 1; off < 16; off <<= 1) mx = fmaxf(mx, __shfl_xor(mx, off, 64));
            float sum = 0.0f;
            #pragma unroll
            for (int nt = 0; nt < 8; ++nt) sum += expf(acc2[nt][r] - mx);
            #pragma unroll
            for (int off = 1; off < 16; off <<= 1) sum += __shfl_xor(sum, off, 64);
            float ls = mx + logf(sum);
            int rg = R0 + quad * 4 + r;
            #pragma unroll
            for (int nt = 0; nt < 8; ++nt)
                lsout[(size_t)rg * DIM + nt * 16 + l16] = acc2[nt][r] - ls;
        }
    }
}

extern "C" void kernel_launch(void* const* d_in, const int* in_sizes, int n_in,
                              void* d_out, int out_size, void* d_ws, size_t ws_size,
                              hipStream_t stream) {
    const float* x   = (const float*)d_in[0];
    const int*   ei  = (const int*)d_in[1];
    const float* W1  = (const float*)d_in[2];
    const float* b1  = (const float*)d_in[3];
    const float* g1  = (const float*)d_in[4];
    const float* be1 = (const float*)d_in[5];
    const float* m1  = (const float*)d_in[6];
    const float* v1  = (const float*)d_in[7];
    const float* W2  = (const float*)d_in[8];
    const float* b2  = (const float*)d_in[9];
    const float* eps = (const float*)d_in[10];
    const float* go  = (const float*)d_in[11];
    const float* bo  = (const float*)d_in[12];
    const float* mo  = (const float*)d_in[13];
    const float* vo  = (const float*)d_in[14];

    char* ws = (char*)d_ws;
    unsigned short* h16 = (unsigned short*)ws;  ws += (size_t)N_NODES * DIM * 2;
    unsigned short* zf = (unsigned short*)ws;   ws += (size_t)MTILES * 2048 * 2;
    _Float16* w1f = (_Float16*)ws;              ws += (size_t)L_LAYERS * 32768 * 2;
    _Float16* w2f = (_Float16*)ws;              ws += (size_t)L_LAYERS * 32768 * 2;
    float* scale1 = (float*)ws; ws += (size_t)L_LAYERS * 256 * 4;
    float* shift1 = (float*)ws; ws += (size_t)L_LAYERS * 256 * 4;
    float* scale2 = (float*)ws; ws += (size_t)L_LAYERS * 128 * 4;
    float* shift2 = (float*)ws; ws += (size_t)L_LAYERS * 128 * 4;
    unsigned int* brec = (unsigned int*)ws; ws += (size_t)NBUCK * BCAP * 4;
    int* gcur    = (int*)ws; ws += 128 * 4;
    int* colbase = (int*)ws; ws += 128 * 4;
    int* rowp    = (int*)ws; ws += (size_t)(N_NODES + 1) * 4;
    unsigned short* col = (unsigned short*)ws; ws += (size_t)E_EDGES * 2;

    // ---- binned CSR build ----
    initcur_kernel<<<1, 128, 0, stream>>>(gcur);
    bin_kernel<<<(E_EDGES + 4095) / 4096, 256, 0, stream>>>(ei, gcur, brec);
    bscan_kernel<<<1, 64, 0, stream>>>(gcur, colbase, rowp);
    bsort_kernel<<<NBUCK, 256, 0, stream>>>(brec, gcur, colbase, rowp, col);

    cvt16_kernel<<<(N_NODES * DIM / 4) / 256, 256, 0, stream>>>((const float4*)x, (f16x4*)h16);
    trans_f16_kernel<<<(2 * L_LAYERS * DIM * 2 * DIM) / 256, 256, 0, stream>>>(W1, W2, w1f, w2f);
    prep_params_kernel<<<5, 256, 0, stream>>>(b1, g1, be1, m1, v1, b2, go, bo, mo, vo,
                                              scale1, shift1, scale2, shift2);

    for (int i = 0; i < L_LAYERS; ++i) {
        aggregate_kernel<<<N_NODES / 4, 256, 0, stream>>>((const unsigned int*)h16,
                                                          rowp, col, eps + i, zf);
        int last = (i == L_LAYERS - 1) ? 1 : 0;
        mlp_kernel<<<MTILES, 64, 0, stream>>>((const _Float16*)zf,
            w1f + (size_t)i * 32768, w2f + (size_t)i * 32768,
            scale1 + i * 256, shift1 + i * 256,
            scale2 + i * 128, shift2 + i * 128,
            last, h16, (float*)d_out);
    }
}

// Round 11
// 325.052 us; speedup vs baseline: 1.1987x; 1.1987x over previous
//
#include <hip/hip_runtime.h>
#include <hip/hip_bf16.h>

#define N_NODES 50000
#define DIM 128
#define E_EDGES 800000
#define L_LAYERS 3
#define MTILES 3125       // 50000/16 exactly
#define MTPAD 3128        // padded tiles (782 blocks * 4 waves)
#define NBUCK 98          // ceil(50000/512)
#define BCAP 9216         // bucket capacity: mean 8192 + 11 sigma
#define BSHIFT 9          // 512 nodes per bucket

typedef __attribute__((ext_vector_type(8))) short short8;
typedef __attribute__((ext_vector_type(4))) float f32x4;
typedef __attribute__((ext_vector_type(2))) _Float16 f16x2;
typedef __attribute__((ext_vector_type(4))) _Float16 f16x4;
typedef __attribute__((ext_vector_type(8))) _Float16 f16x8;

// ---- x fp32 -> fp16 ----
__global__ __launch_bounds__(256) void cvt16_kernel(const float4* __restrict__ in,
                                                    f16x4* __restrict__ out) {
    int i = blockIdx.x * 256 + threadIdx.x;
    float4 v = in[i];
    f16x4 o;
    o[0] = (_Float16)v.x; o[1] = (_Float16)v.y;
    o[2] = (_Float16)v.z; o[3] = (_Float16)v.w;
    out[i] = o;
}

// ---- W1,W2 [L][K][Nn] fp32 -> fragment-contiguous fp16 ----
__global__ __launch_bounds__(256) void trans_f16_kernel(
        const float* __restrict__ w1, const float* __restrict__ w2,
        _Float16* __restrict__ f1, _Float16* __restrict__ f2) {
    int idx = blockIdx.x * 256 + threadIdx.x;
    const int per = DIM * 2 * DIM;             // 32768
    const int tot = L_LAYERS * per;
    const float* w;
    _Float16* f;
    int K, Nn, id;
    if (idx < tot) { w = w1; f = f1; K = DIM; Nn = 2 * DIM; id = idx; }
    else           { w = w2; f = f2; K = 2 * DIM; Nn = DIM; id = idx - tot; }
    int l = id / per;
    int r = id - l * per;
    int k = r / Nn;
    int n = r - k * Nn;
    int KS = K >> 5;
    int off = ((((n >> 4) * KS + (k >> 5)) * 4 + ((k >> 3) & 3)) * 16 + (n & 15)) * 8 + (k & 7);
    f[(size_t)l * per + off] = (_Float16)w[id];
}

// ---- fold bias+BN into per-channel scale/shift ----
__global__ __launch_bounds__(256) void prep_params_kernel(
        const float* __restrict__ b1, const float* __restrict__ g1,
        const float* __restrict__ be1, const float* __restrict__ m1,
        const float* __restrict__ v1, const float* __restrict__ b2,
        const float* __restrict__ go, const float* __restrict__ bo,
        const float* __restrict__ mo, const float* __restrict__ vo,
        float* __restrict__ scale1, float* __restrict__ shift1,
        float* __restrict__ scale2, float* __restrict__ shift2) {
    int idx = blockIdx.x * 256 + threadIdx.x;
    if (idx < L_LAYERS * 256) {
        float s = g1[idx] * rsqrtf(v1[idx] + 1e-5f);
        scale1[idx] = s;
        shift1[idx] = (b1[idx] - m1[idx]) * s + be1[idx];
    }
    int idx2 = idx - L_LAYERS * 256;
    if (idx2 >= 0 && idx2 < L_LAYERS * 128) {
        int l = idx2 >> 7;
        if (l < L_LAYERS - 1) {
            float s = go[idx2] * rsqrtf(vo[idx2] + 1e-5f);
            scale2[idx2] = s;
            shift2[idx2] = (b2[idx2] - mo[idx2]) * s + bo[idx2];
        } else {
            scale2[idx2] = 1.0f;
            shift2[idx2] = b2[idx2];
        }
    }
}

// ================= binned CSR build =================

__global__ void initcur_kernel(int* __restrict__ gcur) {
    int t = threadIdx.x;
    if (t < NBUCK) gcur[t] = t * BCAP;
}

__global__ __launch_bounds__(256) void bin_kernel(const int* __restrict__ ei,
                                                  int* __restrict__ gcur,
                                                  unsigned int* __restrict__ brec) {
    __shared__ int cnt[NBUCK];
    __shared__ int off[NBUCK];
    __shared__ int gbase[NBUCK];
    __shared__ unsigned int rec[4096];
    const int t = threadIdx.x;
    const int start = blockIdx.x * 4096;
    for (int i = t; i < NBUCK; i += 256) cnt[i] = 0;
    __syncthreads();
    unsigned int myrec[16];
    unsigned int mypos[16];
    int nmine = 0;
    #pragma unroll
    for (int i = 0; i < 16; ++i) {
        int e = start + i * 256 + t;
        if (e < E_EDGES) {
            int src = ei[e];
            int dst = ei[E_EDGES + e];
            int b = dst >> BSHIFT;
            int idx = atomicAdd(&cnt[b], 1);
            myrec[i] = ((unsigned int)(dst & 511) << 16) | (unsigned int)src;
            mypos[i] = ((unsigned int)b << 16) | (unsigned int)idx;
            nmine = i + 1;
        }
    }
    __syncthreads();
    if (t == 0) {
        int s = 0;
        for (int b = 0; b < NBUCK; ++b) { off[b] = s; s += cnt[b]; }
    }
    __syncthreads();
    #pragma unroll
    for (int i = 0; i < 16; ++i) {
        if (i < nmine) {
            int b = mypos[i] >> 16;
            int idx = mypos[i] & 0xFFFF;
            rec[off[b] + idx] = myrec[i];
        }
    }
    __syncthreads();
    if (t < NBUCK && cnt[t] > 0) gbase[t] = atomicAdd(&gcur[t], cnt[t]);
    __syncthreads();
    const int wv = t >> 6, lane = t & 63;
    for (int b = wv; b < NBUCK; b += 4) {
        int c = cnt[b], o = off[b], g = gbase[b];
        for (int j = lane; j < c; j += 64)
            brec[g + j] = rec[o + j];
    }
}

__global__ void bscan_kernel(const int* __restrict__ gcur, int* __restrict__ colbase,
                             int* __restrict__ rowp) {
    if (threadIdx.x == 0) {
        int s = 0;
        for (int b = 0; b < NBUCK; ++b) {
            colbase[b] = s;
            s += gcur[b] - b * BCAP;
        }
        rowp[N_NODES] = E_EDGES;
    }
}

__global__ __launch_bounds__(256) void bsort_kernel(const unsigned int* __restrict__ brec,
                                                    const int* __restrict__ gcur,
                                                    const int* __restrict__ colbase,
                                                    int* __restrict__ rowp,
                                                    unsigned short* __restrict__ col) {
    __shared__ int ncnt[512];
    __shared__ int noff[512];
    __shared__ int wsum[4];
    __shared__ unsigned short srcbuf[BCAP];
    const int b = blockIdx.x;
    const int t = threadIdx.x;
    const int lane = t & 63;
    const int wv = t >> 6;
    const int cnt = gcur[b] - b * BCAP;
    const unsigned int* r = brec + (size_t)b * BCAP;
    for (int i = t; i < 512; i += 256) ncnt[i] = 0;
    __syncthreads();
    for (int j = t; j < cnt; j += 256)
        atomicAdd(&ncnt[r[j] >> 16], 1);
    __syncthreads();
    int a0 = ncnt[2 * t], a1 = ncnt[2 * t + 1];
    int pair = a0 + a1;
    int inc = pair;
    #pragma unroll
    for (int d = 1; d < 64; d <<= 1) {
        int u = __shfl_up(inc, d, 64);
        if (lane >= d) inc += u;
    }
    if (lane == 63) wsum[wv] = inc;
    __syncthreads();
    int wo = 0;
    if (wv > 0) wo = wsum[0];
    if (wv > 1) wo += wsum[1];
    if (wv > 2) wo += wsum[2];
    int excl = wo + inc - pair;
    noff[2 * t] = excl;
    noff[2 * t + 1] = excl + a0;
    __syncthreads();
    const int n0 = b << BSHIFT;
    const int cb = colbase[b];
    for (int i = t; i < 512; i += 256) {
        int node = n0 + i;
        if (node < N_NODES) rowp[node] = cb + noff[i];
    }
    for (int i = t; i < 512; i += 256) ncnt[i] = noff[i];
    __syncthreads();
    for (int j = t; j < cnt; j += 256) {
        unsigned int v = r[j];
        int pos = atomicAdd(&ncnt[v >> 16], 1);
        srcbuf[pos] = (unsigned short)(v & 0xFFFFu);
    }
    __syncthreads();
    unsigned short* cp = col + cb;
    for (int j = t; j < cnt; j += 256) cp[j] = srcbuf[j];
}

// ---- aggregation: z = (1+eps)*h[i] + sum_j h[j]; h fp16, z fp16 A-frag order ----
__global__ __launch_bounds__(256) void aggregate_kernel(
        const unsigned int* __restrict__ h16,
        const int* __restrict__ row, const unsigned short* __restrict__ col,
        const float* __restrict__ epsp,
        unsigned short* __restrict__ zf) {
    int wv = threadIdx.x >> 6;
    int lane = threadIdx.x & 63;
    int node = blockIdx.x * 4 + wv;                  // grid = 12500 exactly
    size_t base = (size_t)node * 64;
    float s = 1.0f + epsp[0];
    f16x2 hv = __builtin_bit_cast(f16x2, h16[base + lane]);
    float ax = s * (float)hv[0], ay = s * (float)hv[1];
    int e = row[node], e1 = row[node + 1];
    for (; e + 8 <= e1; e += 8) {
        int c0 = col[e],     c1 = col[e + 1], c2 = col[e + 2], c3 = col[e + 3];
        int c4 = col[e + 4], c5 = col[e + 5], c6 = col[e + 6], c7 = col[e + 7];
        f16x2 v0 = __builtin_bit_cast(f16x2, h16[(size_t)c0 * 64 + lane]);
        f16x2 v1 = __builtin_bit_cast(f16x2, h16[(size_t)c1 * 64 + lane]);
        f16x2 v2 = __builtin_bit_cast(f16x2, h16[(size_t)c2 * 64 + lane]);
        f16x2 v3 = __builtin_bit_cast(f16x2, h16[(size_t)c3 * 64 + lane]);
        f16x2 v4 = __builtin_bit_cast(f16x2, h16[(size_t)c4 * 64 + lane]);
        f16x2 v5 = __builtin_bit_cast(f16x2, h16[(size_t)c5 * 64 + lane]);
        f16x2 v6 = __builtin_bit_cast(f16x2, h16[(size_t)c6 * 64 + lane]);
        f16x2 v7 = __builtin_bit_cast(f16x2, h16[(size_t)c7 * 64 + lane]);
        ax += (((float)v0[0] + (float)v1[0]) + ((float)v2[0] + (float)v3[0]))
            + (((float)v4[0] + (float)v5[0]) + ((float)v6[0] + (float)v7[0]));
        ay += (((float)v0[1] + (float)v1[1]) + ((float)v2[1] + (float)v3[1]))
            + (((float)v4[1] + (float)v5[1]) + ((float)v6[1] + (float)v7[1]));
    }
    for (; e < e1; ++e) {
        f16x2 v = __builtin_bit_cast(f16x2, h16[(size_t)col[e] * 64 + lane]);
        ax += (float)v[0];
        ay += (float)v[1];
    }
    unsigned short ux = __builtin_bit_cast(unsigned short, (_Float16)ax);
    unsigned short uy = __builtin_bit_cast(unsigned short, (_Float16)ay);
    int mt = node >> 4, r16 = node & 15;
    int ks = lane >> 4, quad = (lane >> 2) & 3, jb = (lane * 2) & 7;
    size_t zo = (((size_t)(mt * 4 + ks)) * 4 + quad) * 128 + r16 * 8 + jb;
    *(ushort2*)(zf + zo) = make_ushort2(ux, uy);
}

// ---- fused MLP: 4 waves/block (64 rows), weights staged per K-chunk into
// shared LDS (32KB buffer reused w1->w2), B-fragments read from LDS.
// grid = 782 ; block 256. LDS = 32KB wbuf + 4 x 4.25KB tbuf = ~50KB -> 3 blk/CU.
__global__ __launch_bounds__(256) void mlp_kernel(
        const _Float16* __restrict__ zf,
        const _Float16* __restrict__ w1f, const _Float16* __restrict__ w2f,
        const float* __restrict__ scale1, const float* __restrict__ shift1,
        const float* __restrict__ scale2, const float* __restrict__ shift2,
        int last,
        unsigned short* __restrict__ h16out, float* __restrict__ lsout) {
    __shared__ _Float16 wbuf[16384];      // 32KB staged weight chunk (w1 then w2)
    __shared__ _Float16 tbuf[4][2176];    // per-wave hidden fragments (16 planes*136)
    const int tid = threadIdx.x;
    const int wave = tid >> 6;
    const int lane = tid & 63;
    const int quad = lane >> 4;
    const int l16 = lane & 15;
    const int mt = blockIdx.x * 4 + wave;        // < MTPAD (zf padded)
    const int R0 = mt * 16;

    // A fragments (16 rows x K=128)
    f16x8 ah[4];
    #pragma unroll
    for (int ks = 0; ks < 4; ++ks)
        ah[ks] = *(const f16x8*)(zf + (((size_t)(mt * 4 + ks)) << 9) + lane * 8);

    f32x4 acc2[8] = {};
    #pragma unroll
    for (int c = 0; c < 2; ++c) {
        // ---- stage w1 chunk c: 16384 halfwords contiguous ----
        {
            const _Float16* g = w1f + c * 16384 + tid * 8;
            _Float16* l = wbuf + tid * 8;
            #pragma unroll
            for (int j = 0; j < 8; ++j)
                *(f16x8*)(l + j * 2048) = *(const f16x8*)(g + j * 2048);
        }
        __syncthreads();
        // ---- phase 1: hidden cols [128c,128c+128), B from LDS ----
        #pragma unroll
        for (int ntl = 0; ntl < 8; ++ntl) {
            f32x4 acc = {};
            #pragma unroll
            for (int ks = 0; ks < 4; ++ks) {
                f16x8 b = *(const f16x8*)&wbuf[(ntl * 4 + ks) * 512 + lane * 8];
                acc = __builtin_amdgcn_mfma_f32_16x16x32_f16(ah[ks], b, acc, 0, 0, 0);
            }
            int cg = (c * 8 + ntl) * 16 + l16;
            float sc = scale1[cg];
            float sh = shift1[cg];
            int plane = (cg >> 3) & 15;
            int basei = plane * 136 + (cg & 7);
            #pragma unroll
            for (int r = 0; r < 4; ++r) {
                float val = fmaxf(acc[r] * sc + sh, 0.0f);
                tbuf[wave][basei + (quad * 4 + r) * 8] = (_Float16)val;
            }
        }
        __syncthreads();
        // ---- stage w2 chunk c: 8 pieces of 2048 halfwords ----
        {
            #pragma unroll
            for (int nt = 0; nt < 8; ++nt) {
                *(f16x8*)&wbuf[nt * 2048 + tid * 8] =
                    *(const f16x8*)(w2f + (((size_t)(nt * 8 + c * 4)) << 9) + tid * 8);
            }
        }
        __syncthreads();
        // ---- phase 2: k in [128c,128c+128), B from LDS ----
        #pragma unroll
        for (int ks4 = 0; ks4 < 4; ++ks4) {
            int po = (ks4 * 4 + quad) * 136 + l16 * 8;
            f16x8 a2 = *(const f16x8*)&tbuf[wave][po];
            #pragma unroll
            for (int nt = 0; nt < 8; ++nt) {
                f16x8 b = *(const f16x8*)&wbuf[(nt * 4 + ks4) * 512 + lane * 8];
                acc2[nt] = __builtin_amdgcn_mfma_f32_16x16x32_f16(a2, b, acc2[nt], 0, 0, 0);
            }
        }
        __syncthreads();
    }

    #pragma unroll
    for (int nt = 0; nt < 8; ++nt) {
        int cg = nt * 16 + l16;
        float sc = scale2[cg];
        float sh = shift2[cg];
        #pragma unroll
        for (int r = 0; r < 4; ++r)
            acc2[nt][r] = acc2[nt][r] * sc + sh;
    }
    if (!last) {
        #pragma unroll
        for (int nt = 0; nt < 8; ++nt) {
            int cg = nt * 16 + l16;
            #pragma unroll
            for (int r = 0; r < 4; ++r) {
                int rg = R0 + quad * 4 + r;
                if (rg < N_NODES) {
                    float val = fmaxf(acc2[nt][r], 0.0f);
                    h16out[(size_t)rg * DIM + cg] =
                        __builtin_bit_cast(unsigned short, (_Float16)val);
                }
            }
        }
    } else {
        #pragma unroll
        for (int r = 0; r < 4; ++r) {
            float mx = acc2[0][r];
            #pragma unroll
            for (int nt = 1; nt < 8; ++nt) mx = fmaxf(mx, acc2[nt][r]);
            #pragma unroll
            for (int off = 1; off < 16; off <<= 1) mx = fmaxf(mx, __shfl_xor(mx, off, 64));
            float sum = 0.0f;
            #pragma unroll
            for (int nt = 0; nt < 8; ++nt) sum += expf(acc2[nt][r] - mx);
            #pragma unroll
            for (int off = 1; off < 16; off <<= 1) sum += __shfl_xor(sum, off, 64);
            float ls = mx + logf(sum);
            int rg = R0 + quad * 4 + r;
            if (rg < N_NODES) {
                #pragma unroll
                for (int nt = 0; nt < 8; ++nt)
                    lsout[(size_t)rg * DIM + nt * 16 + l16] = acc2[nt][r] - ls;
            }
        }
    }
}

extern "C" void kernel_launch(void* const* d_in, const int* in_sizes, int n_in,
                              void* d_out, int out_size, void* d_ws, size_t ws_size,
                              hipStream_t stream) {
    const float* x   = (const float*)d_in[0];
    const int*   ei  = (const int*)d_in[1];
    const float* W1  = (const float*)d_in[2];
    const float* b1  = (const float*)d_in[3];
    const float* g1  = (const float*)d_in[4];
    const float* be1 = (const float*)d_in[5];
    const float* m1  = (const float*)d_in[6];
    const float* v1  = (const float*)d_in[7];
    const float* W2  = (const float*)d_in[8];
    const float* b2  = (const float*)d_in[9];
    const float* eps = (const float*)d_in[10];
    const float* go  = (const float*)d_in[11];
    const float* bo  = (const float*)d_in[12];
    const float* mo  = (const float*)d_in[13];
    const float* vo  = (const float*)d_in[14];

    char* ws = (char*)d_ws;
    unsigned short* h16 = (unsigned short*)ws;  ws += (size_t)N_NODES * DIM * 2;
    unsigned short* zf = (unsigned short*)ws;   ws += (size_t)MTPAD * 2048 * 2;
    _Float16* w1f = (_Float16*)ws;              ws += (size_t)L_LAYERS * 32768 * 2;
    _Float16* w2f = (_Float16*)ws;              ws += (size_t)L_LAYERS * 32768 * 2;
    float* scale1 = (float*)ws; ws += (size_t)L_LAYERS * 256 * 4;
    float* shift1 = (float*)ws; ws += (size_t)L_LAYERS * 256 * 4;
    float* scale2 = (float*)ws; ws += (size_t)L_LAYERS * 128 * 4;
    float* shift2 = (float*)ws; ws += (size_t)L_LAYERS * 128 * 4;
    unsigned int* brec = (unsigned int*)ws; ws += (size_t)NBUCK * BCAP * 4;
    int* gcur    = (int*)ws; ws += 128 * 4;
    int* colbase = (int*)ws; ws += 128 * 4;
    int* rowp    = (int*)ws; ws += (size_t)(N_NODES + 1) * 4;
    unsigned short* col = (unsigned short*)ws; ws += (size_t)E_EDGES * 2;

    // ---- binned CSR build ----
    initcur_kernel<<<1, 128, 0, stream>>>(gcur);
    bin_kernel<<<(E_EDGES + 4095) / 4096, 256, 0, stream>>>(ei, gcur, brec);
    bscan_kernel<<<1, 64, 0, stream>>>(gcur, colbase, rowp);
    bsort_kernel<<<NBUCK, 256, 0, stream>>>(brec, gcur, colbase, rowp, col);

    cvt16_kernel<<<(N_NODES * DIM / 4) / 256, 256, 0, stream>>>((const float4*)x, (f16x4*)h16);
    trans_f16_kernel<<<(2 * L_LAYERS * DIM * 2 * DIM) / 256, 256, 0, stream>>>(W1, W2, w1f, w2f);
    prep_params_kernel<<<5, 256, 0, stream>>>(b1, g1, be1, m1, v1, b2, go, bo, mo, vo,
                                              scale1, shift1, scale2, shift2);

    for (int i = 0; i < L_LAYERS; ++i) {
        aggregate_kernel<<<N_NODES / 4, 256, 0, stream>>>((const unsigned int*)h16,
                                                          rowp, col, eps + i, zf);
        int last = (i == L_LAYERS - 1) ? 1 : 0;
        mlp_kernel<<<782, 256, 0, stream>>>((const _Float16*)zf,
            w1f + (size_t)i * 32768, w2f + (size_t)i * 32768,
            scale1 + i * 256, shift1 + i * 256,
            scale2 + i * 128, shift2 + i * 128,
            last, h16, (float*)d_out);
    }
}